// Round 24
// baseline (102.456 us; speedup 1.0000x reference)
//
#include <hip/hip_runtime.h>
#include <hip/hip_bf16.h>
#include <cstddef>

#define NB     2
#define NA     6
#define NWIN   64
#define NTOK   384
#define DIM    128
#define NHEADS 4
#define DHEAD  32

typedef __attribute__((ext_vector_type(8))) short short8;   // 8 bf16 = 4 VGPRs
typedef __attribute__((ext_vector_type(4))) float f32x4;

__device__ __forceinline__ unsigned short f2bf(float f) {
    __hip_bfloat16 h = __float2bfloat16(f);
    return *reinterpret_cast<unsigned short*>(&h);
}
__device__ __forceinline__ float bf2f(unsigned short u) {
    union { unsigned int i; float f; } x; x.i = ((unsigned int)u) << 16; return x.f;
}
__device__ __forceinline__ unsigned int pk2(float a, float b) {
    return (unsigned int)f2bf(a) | ((unsigned int)f2bf(b) << 16);
}

// q pre-scale includes log2(e): softmax uses exp2
#define QSCALE (0.17677669529663687f * 1.4426950408889634f)

// ---------------------------------------------------------------------------
// Weight prep: blocks 0..191 convert wt[mat][col][k]=bf16(lnw_k*W[k][col]*qs),
// blocks 192..194 column sums scol/tcol (8-way unrolled chains).
// ---------------------------------------------------------------------------
__global__ __launch_bounds__(256) void wprep_kernel(
    const float* __restrict__ wq, const float* __restrict__ wk,
    const float* __restrict__ wv,
    const float* __restrict__ lnqw, const float* __restrict__ lnkw,
    const float* __restrict__ lnvw,
    const float* __restrict__ lnqb, const float* __restrict__ lnkb,
    const float* __restrict__ lnvb,
    const float* __restrict__ bq, const float* __restrict__ bk,
    const float* __restrict__ bv, const float* __restrict__ gate,
    unsigned short* __restrict__ wt,
    float* __restrict__ scol, float* __restrict__ tcol)
{
    const int bid = blockIdx.x;
    if (bid < 192) {
        const int e = bid * 256 + threadIdx.x;   // 0..49151
        const int mat = e >> 14, i = e & 16383;
        const int kk = i >> 7, c = i & 127;
        const float* src = (mat == 0) ? wq : (mat == 1) ? wk : wv;
        const float* lnw = (mat == 0) ? lnqw : (mat == 1) ? lnkw : lnvw;
        const float s = (mat == 0) ? (QSCALE * gate[c >> 5]) : 1.0f;
        wt[(mat << 14) + c * DIM + kk] = f2bf(src[i] * lnw[kk] * s);
        return;
    }
    const int mat = bid - 192;
    const int c = threadIdx.x;
    if (c >= DIM) return;
    const float* src  = (mat == 0) ? wq : (mat == 1) ? wk : wv;
    const float* lnw  = (mat == 0) ? lnqw : (mat == 1) ? lnkw : lnvw;
    const float* lnb  = (mat == 0) ? lnqb : (mat == 1) ? lnkb : lnvb;
    const float* bias = (mat == 0) ? bq : (mat == 1) ? bk : bv;
    float sa[8] = {0.f,0.f,0.f,0.f,0.f,0.f,0.f,0.f};
    float ta[8] = {0.f,0.f,0.f,0.f,0.f,0.f,0.f,0.f};
#pragma unroll
    for (int k0 = 0; k0 < DIM; k0 += 8) {
        float w0 = src[(k0+0)*DIM+c], w1 = src[(k0+1)*DIM+c];
        float w2 = src[(k0+2)*DIM+c], w3 = src[(k0+3)*DIM+c];
        float w4 = src[(k0+4)*DIM+c], w5 = src[(k0+5)*DIM+c];
        float w6 = src[(k0+6)*DIM+c], w7 = src[(k0+7)*DIM+c];
        sa[0] += lnw[k0+0]*w0; ta[0] += lnb[k0+0]*w0;
        sa[1] += lnw[k0+1]*w1; ta[1] += lnb[k0+1]*w1;
        sa[2] += lnw[k0+2]*w2; ta[2] += lnb[k0+2]*w2;
        sa[3] += lnw[k0+3]*w3; ta[3] += lnb[k0+3]*w3;
        sa[4] += lnw[k0+4]*w4; ta[4] += lnb[k0+4]*w4;
        sa[5] += lnw[k0+5]*w5; ta[5] += lnb[k0+5]*w5;
        sa[6] += lnw[k0+6]*w6; ta[6] += lnb[k0+6]*w6;
        sa[7] += lnw[k0+7]*w7; ta[7] += lnb[k0+7]*w7;
    }
    const float s = ((sa[0]+sa[1])+(sa[2]+sa[3]))+((sa[4]+sa[5])+(sa[6]+sa[7]));
    const float t = ((ta[0]+ta[1])+(ta[2]+ta[3]))+((ta[4]+ta[5])+(ta[6]+ta[7]));
    const float qs = (mat == 0) ? (QSCALE * gate[c >> 5]) : 1.0f;
    scol[mat * DIM + c] = s * qs;
    tcol[mat * DIM + c] = (t + bias[c]) * qs;
}

#define ACC8(p, q) do { \
    s  += ((p.x + p.y) + (p.z + p.w)) + ((q.x + q.y) + (q.z + q.w)); \
    s2 += ((p.x*p.x + p.y*p.y) + (p.z*p.z + p.w*p.w)) \
        + ((q.x*q.x + q.y*q.y) + (q.z*q.z + q.w*q.w)); } while (0)
#define CVT8(p, q) ({ short8 o_; \
    o_[0]=(short)f2bf(p.x); o_[1]=(short)f2bf(p.y); o_[2]=(short)f2bf(p.z); o_[3]=(short)f2bf(p.w); \
    o_[4]=(short)f2bf(q.x); o_[5]=(short)f2bf(q.y); o_[6]=(short)f2bf(q.z); o_[7]=(short)f2bf(q.w); o_; })

// LN one 16-token unit: lane (g,qc) owns token qc's dims {c*32+8g..+7};
// raw bf16 frags + stats (LN folded into W, so frags are raw x).
__device__ __forceinline__ void ln_unit(
    const float* __restrict__ xp, float& mu, float& rs, short8* __restrict__ af)
{
    const float4 u0 = *(const float4*)(xp + 0);
    const float4 u1 = *(const float4*)(xp + 4);
    const float4 u2 = *(const float4*)(xp + 32);
    const float4 u3 = *(const float4*)(xp + 36);
    const float4 u4 = *(const float4*)(xp + 64);
    const float4 u5 = *(const float4*)(xp + 68);
    const float4 u6 = *(const float4*)(xp + 96);
    const float4 u7 = *(const float4*)(xp + 100);
    float s = 0.f, s2 = 0.f;
    ACC8(u0, u1); ACC8(u2, u3); ACC8(u4, u5); ACC8(u6, u7);
    s  += __shfl_xor(s, 16);  s  += __shfl_xor(s, 32);
    s2 += __shfl_xor(s2, 16); s2 += __shfl_xor(s2, 32);
    mu = s * (1.0f / 128.0f);
    rs = rsqrtf(s2 * (1.0f / 128.0f) - mu * mu + 1e-5f);
    af[0] = CVT8(u0, u1); af[1] = CVT8(u2, u3);
    af[2] = CVT8(u4, u5); af[3] = CVT8(u6, u7);
}

// ---------------------------------------------------------------------------
// FUSED proj+attention: one block per (b,h,l); 384 thr (6 waves x 64 tokens).
// Phase A: stage head-h W cols (24 KB LDS, r23 OOB col/chunk decomposition
//   FIXED: col=rem>>4, j=rem&15); per wave 4x16-token units: LN + proj via
//   MFMA. K,V -> LDS; Q D^T stays in registers. One barrier.
// Phase B: flash attention; K/V frags from LDS; Q and P A-frags built by
//   register shuffles (no P LDS, no extra barriers). Out: a bf16.
// LDS 72.5 KB -> 2 blocks/CU. XCD swizzle: 4 heads of one (b,l) on one XCD.
// ---------------------------------------------------------------------------
__global__ __launch_bounds__(384) void fattn_kernel(
    const float* __restrict__ qx, const float* __restrict__ kx,
    const float* __restrict__ vx,
    const unsigned short* __restrict__ wt,
    const float* __restrict__ scol, const float* __restrict__ tcol,
    unsigned short* __restrict__ aout)
{
    __shared__ unsigned short Wl[3 * 32 * DIM];   // 24 KB [m][lc][k] swizzled
    __shared__ unsigned short Kl[NTOK * 32];      // 24 KB [t][d]
    __shared__ unsigned short Vl[32 * 392];       // 24.5 KB [d][t], pitch 392

    // XCD swizzle: id = (group/8)*32 + h*8 + (group%8)
    const int id = blockIdx.x;
    const int r_ = id & 7, rest = id >> 3;
    const int h = rest & 3, gq = rest >> 2;
    const int group = gq * 8 + r_;                // b*64 + l
    const int b = group >> 6, l = group & 63;

    const int wv_ = threadIdx.x / 64;             // 0..5
    const int lane = threadIdx.x & 63;
    const int g = lane >> 4, qc = lane & 15;
    const int swz = (qc & 7) << 3;

    // ---- stage W (head h, 3 mats): 1536 16B chunks, 4/thread.
    //      per-matrix: 512 chunks = 32 cols x 16 chunks; col=rem>>4, j=rem&15.
    {
        const int t0 = threadIdx.x;
        const int c0 = t0, c1 = t0 + 384, c2 = t0 + 768, c3 = t0 + 1152;
#define WSRC(c) (wt + ((c) >> 9) * 16384 + (h * 32 + (((c) & 511) >> 4)) * DIM + ((c) & 15) * 8)
        const short8 wb0 = *(const short8*)WSRC(c0);
        const short8 wb1 = *(const short8*)WSRC(c1);
        const short8 wb2 = *(const short8*)WSRC(c2);
        const short8 wb3 = *(const short8*)WSRC(c3);
#undef WSRC
#define WDST(c, v) { const int m_ = (c) >> 9, rem_ = (c) & 511; \
        const int col_ = rem_ >> 4, jj_ = rem_ & 15; \
        *(short8*)&Wl[m_ * 4096 + col_ * DIM + ((jj_ ^ (col_ & 7)) * 8)] = v; }
        WDST(c0, wb0); WDST(c1, wb1); WDST(c2, wb2); WDST(c3, wb3);
#undef WDST
    }
    __syncthreads();

    const f32x4 z = {0.f, 0.f, 0.f, 0.f};
    uint2 qd[4][2];                               // Q D^T per unit/ct (static idx)

#pragma unroll
    for (int j = 0; j < 4; ++j) {
        const int u = 4 * wv_ + j;                // global unit 0..23
        const int n = u >> 2;                     // agent
        const int tloc = 16 * u;                  // window-token base
        const size_t xoff = (((size_t)(b * NA + n) * NWIN + l) * 64 + (u & 3) * 16 + qc) * DIM + 8 * g;

        // ---- q (swapped: D^T lane=token qc, cols ct*16+4g..+3) -> regs ----
        {
            float mu, rs; short8 af[4];
            ln_unit(qx + xoff, mu, rs, af);
#pragma unroll
            for (int ct = 0; ct < 2; ++ct) {
                const int lc = ct * 16 + qc;
                f32x4 acc = z;
#pragma unroll
                for (int c = 0; c < 4; ++c) {
                    const short8 wf = *(const short8*)&Wl[lc * DIM + ((c * 32 + 8 * g) ^ swz)];
                    acc = __builtin_amdgcn_mfma_f32_16x16x32_bf16(wf, af[c], acc, 0, 0, 0);
                }
                const float4 s4 = *(const float4*)&scol[h * 32 + ct * 16 + 4 * g];
                const float4 t4 = *(const float4*)&tcol[h * 32 + ct * 16 + 4 * g];
                qd[j][ct].x = pk2(rs * (acc[0] - mu * s4.x) + t4.x,
                                  rs * (acc[1] - mu * s4.y) + t4.y);
                qd[j][ct].y = pk2(rs * (acc[2] - mu * s4.z) + t4.z,
                                  rs * (acc[3] - mu * s4.w) + t4.w);
            }
        }
        // ---- k (swapped) -> Kl[t][d] ----
        {
            float mu, rs; short8 af[4];
            ln_unit(kx + xoff, mu, rs, af);
#pragma unroll
            for (int ct = 0; ct < 2; ++ct) {
                const int lc = ct * 16 + qc;
                f32x4 acc = z;
#pragma unroll
                for (int c = 0; c < 4; ++c) {
                    const short8 wf = *(const short8*)&Wl[4096 + lc * DIM + ((c * 32 + 8 * g) ^ swz)];
                    acc = __builtin_amdgcn_mfma_f32_16x16x32_bf16(wf, af[c], acc, 0, 0, 0);
                }
                const float4 s4 = *(const float4*)&scol[DIM + h * 32 + ct * 16 + 4 * g];
                const float4 t4 = *(const float4*)&tcol[DIM + h * 32 + ct * 16 + 4 * g];
                ushort4 o;
                o.x = f2bf(rs * (acc[0] - mu * s4.x) + t4.x);
                o.y = f2bf(rs * (acc[1] - mu * s4.y) + t4.y);
                o.z = f2bf(rs * (acc[2] - mu * s4.z) + t4.z);
                o.w = f2bf(rs * (acc[3] - mu * s4.w) + t4.w);
                *(ushort4*)&Kl[(tloc + qc) * 32 + ct * 16 + 4 * g] = o;
            }
        }
        // ---- v (unswapped: D rows=tokens 4g+r, col lc) -> Vl[d][t] ----
        {
            float mu, rs; short8 af[4];
            ln_unit(vx + xoff, mu, rs, af);
            float m4[4], r4[4];
#pragma unroll
            for (int r = 0; r < 4; ++r) {
                m4[r] = __shfl(mu, 4 * g + r);
                r4[r] = __shfl(rs, 4 * g + r);
            }
#pragma unroll
            for (int ct = 0; ct < 2; ++ct) {
                const int lc = ct * 16 + qc;
                f32x4 acc = z;
#pragma unroll
                for (int c = 0; c < 4; ++c) {
                    const short8 wf = *(const short8*)&Wl[8192 + lc * DIM + ((c * 32 + 8 * g) ^ swz)];
                    acc = __builtin_amdgcn_mfma_f32_16x16x32_bf16(af[c], wf, acc, 0, 0, 0);
                }
                const float s_c = scol[2 * DIM + h * 32 + lc];
                const float t_c = tcol[2 * DIM + h * 32 + lc];
                ushort4 o;
                o.x = f2bf(r4[0] * (acc[0] - m4[0] * s_c) + t_c);
                o.y = f2bf(r4[1] * (acc[1] - m4[1] * s_c) + t_c);
                o.z = f2bf(r4[2] * (acc[2] - m4[2] * s_c) + t_c);
                o.w = f2bf(r4[3] * (acc[3] - m4[3] * s_c) + t_c);
                *(ushort4*)&Vl[lc * 392 + tloc + 4 * g] = o;
            }
        }
    }
    __syncthreads();   // K,V staged; everyone done with W

    // ---- flash attention; P/Q A-frags via register shuffles ----
    const int srcA = (((2 * g) & 3) << 4) + qc;
    const int srcB = (((2 * g + 1) & 3) << 4) + qc;
    const bool lo = (g < 2);

#pragma unroll
    for (int jp = 0; jp < 2; ++jp) {
        short8 qfA, qfB;
        {
            const int d0 = qd[2 * jp][0].x, d1 = qd[2 * jp][0].y;
            const int d2 = qd[2 * jp][1].x, d3 = qd[2 * jp][1].y;
            const int a0 = __shfl(d0, srcA), a1 = __shfl(d1, srcA);
            const int a2 = __shfl(d2, srcA), a3 = __shfl(d3, srcA);
            const int b0 = __shfl(d0, srcB), b1 = __shfl(d1, srcB);
            const int b2 = __shfl(d2, srcB), b3 = __shfl(d3, srcB);
            int4 t; t.x = lo ? a0 : a2; t.y = lo ? a1 : a3;
            t.z = lo ? b0 : b2; t.w = lo ? b1 : b3;
            qfA = *(short8*)&t;
        }
        {
            const int d0 = qd[2 * jp + 1][0].x, d1 = qd[2 * jp + 1][0].y;
            const int d2 = qd[2 * jp + 1][1].x, d3 = qd[2 * jp + 1][1].y;
            const int a0 = __shfl(d0, srcA), a1 = __shfl(d1, srcA);
            const int a2 = __shfl(d2, srcA), a3 = __shfl(d3, srcA);
            const int b0 = __shfl(d0, srcB), b1 = __shfl(d1, srcB);
            const int b2 = __shfl(d2, srcB), b3 = __shfl(d3, srcB);
            int4 t; t.x = lo ? a0 : a2; t.y = lo ? a1 : a3;
            t.z = lo ? b0 : b2; t.w = lo ? b1 : b3;
            qfB = *(short8*)&t;
        }

        f32x4 oA0 = z, oA1 = z, oB0 = z, oB1 = z;
        float psA = 0.f, psB = 0.f;

        for (int kc = 0; kc < 12; ++kc) {
            const int k0 = kc * 32;
            const short8 ka0 = *(const short8*)&Kl[(k0 + qc) * 32 + 8 * g];
            const short8 ka1 = *(const short8*)&Kl[(k0 + 16 + qc) * 32 + 8 * g];
            const short8 vb0 = *(const short8*)&Vl[qc * 392 + k0 + 8 * g];
            const short8 vb1 = *(const short8*)&Vl[(16 + qc) * 392 + k0 + 8 * g];
            {   // tile A
                f32x4 s0 = __builtin_amdgcn_mfma_f32_16x16x32_bf16(ka0, qfA, z, 0, 0, 0);
                f32x4 s1 = __builtin_amdgcn_mfma_f32_16x16x32_bf16(ka1, qfA, z, 0, 0, 0);
                const float e0 = exp2f(s0[0]), e1 = exp2f(s0[1]), e2 = exp2f(s0[2]), e3 = exp2f(s0[3]);
                const float e4 = exp2f(s1[0]), e5 = exp2f(s1[1]), e6 = exp2f(s1[2]), e7 = exp2f(s1[3]);
                psA += ((e0 + e1) + (e2 + e3)) + ((e4 + e5) + (e6 + e7));
                const int d0 = pk2(e0, e1), d1 = pk2(e2, e3);
                const int d2 = pk2(e4, e5), d3 = pk2(e6, e7);
                const int a0 = __shfl(d0, srcA), a1 = __shfl(d1, srcA);
                const int a2 = __shfl(d2, srcA), a3 = __shfl(d3, srcA);
                const int b0 = __shfl(d0, srcB), b1 = __shfl(d1, srcB);
                const int b2 = __shfl(d2, srcB), b3 = __shfl(d3, srcB);
                int4 t; t.x = lo ? a0 : a2; t.y = lo ? a1 : a3;
                t.z = lo ? b0 : b2; t.w = lo ? b1 : b3;
                const short8 pa = *(short8*)&t;
                oA0 = __builtin_amdgcn_mfma_f32_16x16x32_bf16(pa, vb0, oA0, 0, 0, 0);
                oA1 = __builtin_amdgcn_mfma_f32_16x16x32_bf16(pa, vb1, oA1, 0, 0, 0);
            }
            {   // tile B
                f32x4 s0 = __builtin_amdgcn_mfma_f32_16x16x32_bf16(ka0, qfB, z, 0, 0, 0);
                f32x4 s1 = __builtin_amdgcn_mfma_f32_16x16x32_bf16(ka1, qfB, z, 0, 0, 0);
                const float e0 = exp2f(s0[0]), e1 = exp2f(s0[1]), e2 = exp2f(s0[2]), e3 = exp2f(s0[3]);
                const float e4 = exp2f(s1[0]), e5 = exp2f(s1[1]), e6 = exp2f(s1[2]), e7 = exp2f(s1[3]);
                psB += ((e0 + e1) + (e2 + e3)) + ((e4 + e5) + (e6 + e7));
                const int d0 = pk2(e0, e1), d1 = pk2(e2, e3);
                const int d2 = pk2(e4, e5), d3 = pk2(e6, e7);
                const int a0 = __shfl(d0, srcA), a1 = __shfl(d1, srcA);
                const int a2 = __shfl(d2, srcA), a3 = __shfl(d3, srcA);
                const int b0 = __shfl(d0, srcB), b1 = __shfl(d1, srcB);
                const int b2 = __shfl(d2, srcB), b3 = __shfl(d3, srcB);
                int4 t; t.x = lo ? a0 : a2; t.y = lo ? a1 : a3;
                t.z = lo ? b0 : b2; t.w = lo ? b1 : b3;
                const short8 pa = *(short8*)&t;
                oB0 = __builtin_amdgcn_mfma_f32_16x16x32_bf16(pa, vb0, oB0, 0, 0, 0);
                oB1 = __builtin_amdgcn_mfma_f32_16x16x32_bf16(pa, vb1, oB1, 0, 0, 0);
            }
        }

        // epilogues
        {
            float ps = psA;
            ps += __shfl_xor(ps, 16); ps += __shfl_xor(ps, 32);
            const float inv = 1.0f / ps;
            const int q0 = 64 * wv_ + 16 * (2 * jp);
            const size_t ob = ((size_t)(b * NWIN + l) * NTOK + q0) * (NHEADS * DHEAD) + h * DHEAD + qc;
#pragma unroll
            for (int r = 0; r < 4; ++r) {
                const float iv = __shfl(inv, 4 * g + r);
                aout[ob + (size_t)(4 * g + r) * (NHEADS * DHEAD)]      = f2bf(oA0[r] * iv);
                aout[ob + (size_t)(4 * g + r) * (NHEADS * DHEAD) + 16] = f2bf(oA1[r] * iv);
            }
        }
        {
            float ps = psB;
            ps += __shfl_xor(ps, 16); ps += __shfl_xor(ps, 32);
            const float inv = 1.0f / ps;
            const int q0 = 64 * wv_ + 16 * (2 * jp + 1);
            const size_t ob = ((size_t)(b * NWIN + l) * NTOK + q0) * (NHEADS * DHEAD) + h * DHEAD + qc;
#pragma unroll
            for (int r = 0; r < 4; ++r) {
                const float iv = __shfl(inv, 4 * g + r);
                aout[ob + (size_t)(4 * g + r) * (NHEADS * DHEAD)]      = f2bf(oB0[r] * iv);
                aout[ob + (size_t)(4 * g + r) * (NHEADS * DHEAD) + 16] = f2bf(oB1[r] * iv);
            }
        }
    }
}

// ---------------------------------------------------------------------------
// Output projection: mean over n commutes with (@ wp + bp). One block per
// (b, window, col-half) -> 256 blocks. a is bf16.
// ---------------------------------------------------------------------------
__global__ __launch_bounds__(256) void outproj_kernel(
    const unsigned short* __restrict__ a, const float* __restrict__ wp,
    const float* __restrict__ bp, const float* __restrict__ skip,
    float* __restrict__ outp)
{
    __shared__ float at[DIM * 68];       // abar transposed [dim][w], 34 KB
    __shared__ float wl[DIM * 64];       // [k][64 cols] 32 KB

    const int tid = threadIdx.x;
    const int bid = blockIdx.x;
    const int b = bid >> 7, l = (bid >> 1) & 63, cg = bid & 1;
    const int c0 = cg * 64;

#pragma unroll
    for (int rep = 0; rep < 8; ++rep) {
        const int idx = rep * 256 + tid;
        const int row = idx >> 4, cc4 = idx & 15;
        *(float4*)&wl[row * 64 + cc4 * 4] = *(const float4*)&wp[row * 128 + c0 + cc4 * 4];
    }

    const size_t abase = (size_t)(b * NWIN + l) * NTOK * DIM;
#pragma unroll
    for (int r = 0; r < 32; ++r) {
        const int f = tid + 256 * r;     // f = w*128 + d
        const int w_ = f >> 7, d = f & 127;
        float s = 0.f;
#pragma unroll
        for (int n = 0; n < NA; ++n)
            s += bf2f(a[abase + (size_t)(n * 64 + w_) * DIM + d]);
        at[d * 68 + w_] = s * (1.0f / 6.0f);
    }
    __syncthreads();

    const int cx = tid & 15, ty = tid >> 4;   // 4 cols x 4 tokens per thread
    float acc[4][4];
#pragma unroll
    for (int i = 0; i < 4; ++i)
#pragma unroll
        for (int j = 0; j < 4; ++j) acc[i][j] = 0.f;

#pragma unroll 4
    for (int i = 0; i < DIM; ++i) {
        const float4 wa = *(const float4*)&wl[i * 64 + 4 * cx];
        const float4 aa = *(const float4*)&at[i * 68 + 4 * ty];
        acc[0][0] += aa.x * wa.x; acc[0][1] += aa.x * wa.y; acc[0][2] += aa.x * wa.z; acc[0][3] += aa.x * wa.w;
        acc[1][0] += aa.y * wa.x; acc[1][1] += aa.y * wa.y; acc[1][2] += aa.y * wa.z; acc[1][3] += aa.y * wa.w;
        acc[2][0] += aa.z * wa.x; acc[2][1] += aa.z * wa.y; acc[2][2] += aa.z * wa.z; acc[2][3] += aa.z * wa.w;
        acc[3][0] += aa.w * wa.x; acc[3][1] += aa.w * wa.y; acc[3][2] += aa.w * wa.z; acc[3][3] += aa.w * wa.w;
    }

    const float4 bb = *(const float4*)&bp[c0 + 4 * cx];
#pragma unroll
    for (int u = 0; u < 4; ++u) {
        const int w_ = 4 * ty + u;
        const size_t oidx = ((size_t)(b * NWIN + l) * 64 + w_) * DIM + c0 + 4 * cx;
        const float4 sk = *(const float4*)&skip[oidx];
        float4 o;
        o.x = acc[u][0] + bb.x + sk.x;
        o.y = acc[u][1] + bb.y + sk.y;
        o.z = acc[u][2] + bb.z + sk.z;
        o.w = acc[u][3] + bb.w + sk.w;
        *(float4*)&outp[oidx] = o;
    }
}

extern "C" void kernel_launch(void* const* d_in, const int* in_sizes, int n_in,
                              void* d_out, int out_size, void* d_ws, size_t ws_size,
                              hipStream_t stream) {
    const float* q      = (const float*)d_in[0];
    const float* k      = (const float*)d_in[1];
    const float* v      = (const float*)d_in[2];
    const float* skip   = (const float*)d_in[3];
    const float* gate   = (const float*)d_in[4];
    const float* ln_q_w = (const float*)d_in[5];
    const float* ln_q_b = (const float*)d_in[6];
    const float* ln_k_w = (const float*)d_in[7];
    const float* ln_k_b = (const float*)d_in[8];
    const float* ln_v_w = (const float*)d_in[9];
    const float* ln_v_b = (const float*)d_in[10];
    const float* wq     = (const float*)d_in[11];
    const float* bq     = (const float*)d_in[12];
    const float* wk     = (const float*)d_in[13];
    const float* bk     = (const float*)d_in[14];
    const float* wv     = (const float*)d_in[15];
    const float* bv     = (const float*)d_in[16];
    const float* wp     = (const float*)d_in[17];
    const float* bp     = (const float*)d_in[18];
    float* outp = (float*)d_out;

    const size_t per = (size_t)NB * NWIN * NTOK * DIM;   // 6,291,456 (a elems)
    unsigned short* wt = (unsigned short*)d_ws;          // 3*16384 bf16
    unsigned short* a  = wt + 3 * 16384;                 // [b][l][t][128] bf16
    float* scol = (float*)(a + per);                     // 3*128 f32
    float* tcol = scol + 3 * DIM;

    wprep_kernel<<<195, 256, 0, stream>>>(wq, wk, wv, ln_q_w, ln_k_w, ln_v_w,
                                          ln_q_b, ln_k_b, ln_v_b, bq, bk, bv,
                                          gate, wt, scol, tcol);
    fattn_kernel<<<NB * NHEADS * NWIN, 384, 0, stream>>>(q, k, v, wt, scol, tcol, a);
    outproj_kernel<<<NB * NWIN * 2, 256, 0, stream>>>(a, wp, bp, skip, outp);
}

// Round 25
// 70.428 us; speedup vs baseline: 1.4547x; 1.4547x over previous
//
#include <hip/hip_runtime.h>
#include <hip/hip_bf16.h>
#include <cstddef>

#define NB     2
#define NA     6
#define NWIN   64
#define NTOK   384
#define DIM    128
#define NHEADS 4
#define DHEAD  32

typedef __attribute__((ext_vector_type(8))) short short8;   // 8 bf16 = 4 VGPRs
typedef __attribute__((ext_vector_type(4))) float f32x4;

__device__ __forceinline__ unsigned short f2bf(float f) {
    __hip_bfloat16 h = __float2bfloat16(f);
    return *reinterpret_cast<unsigned short*>(&h);
}
__device__ __forceinline__ float bf2f(unsigned short u) {
    union { unsigned int i; float f; } x; x.i = ((unsigned int)u) << 16; return x.f;
}

#define QSCALE 0.17677669529663687f

// ---------------------------------------------------------------------------
// Weight prep, one launch: blocks 0..191 convert wt, 192..194 column sums.
// ---------------------------------------------------------------------------
__global__ __launch_bounds__(256) void wprep_kernel(
    const float* __restrict__ wq, const float* __restrict__ wk,
    const float* __restrict__ wv,
    const float* __restrict__ lnqw, const float* __restrict__ lnkw,
    const float* __restrict__ lnvw,
    const float* __restrict__ lnqb, const float* __restrict__ lnkb,
    const float* __restrict__ lnvb,
    const float* __restrict__ bq, const float* __restrict__ bk,
    const float* __restrict__ bv, const float* __restrict__ gate,
    unsigned short* __restrict__ wt,
    float* __restrict__ scol, float* __restrict__ tcol)
{
    const int bid = blockIdx.x;
    if (bid < 192) {
        const int e = bid * 256 + threadIdx.x;   // 0..49151
        const int mat = e >> 14, i = e & 16383;
        const int kk = i >> 7, c = i & 127;
        const float* src = (mat == 0) ? wq : (mat == 1) ? wk : wv;
        const float* lnw = (mat == 0) ? lnqw : (mat == 1) ? lnkw : lnvw;
        const float s = (mat == 0) ? (QSCALE * gate[c >> 5]) : 1.0f;
        wt[(mat << 14) + c * DIM + kk] = f2bf(src[i] * lnw[kk] * s);
        return;
    }
    // column sums, 8 independent accumulator chains
    const int mat = bid - 192;
    const int c = threadIdx.x;
    if (c >= DIM) return;
    const float* src  = (mat == 0) ? wq : (mat == 1) ? wk : wv;
    const float* lnw  = (mat == 0) ? lnqw : (mat == 1) ? lnkw : lnvw;
    const float* lnb  = (mat == 0) ? lnqb : (mat == 1) ? lnkb : lnvb;
    const float* bias = (mat == 0) ? bq : (mat == 1) ? bk : bv;
    float sa[8] = {0.f,0.f,0.f,0.f,0.f,0.f,0.f,0.f};
    float ta[8] = {0.f,0.f,0.f,0.f,0.f,0.f,0.f,0.f};
#pragma unroll
    for (int k0 = 0; k0 < DIM; k0 += 8) {
        float w0 = src[(k0+0)*DIM+c], w1 = src[(k0+1)*DIM+c];
        float w2 = src[(k0+2)*DIM+c], w3 = src[(k0+3)*DIM+c];
        float w4 = src[(k0+4)*DIM+c], w5 = src[(k0+5)*DIM+c];
        float w6 = src[(k0+6)*DIM+c], w7 = src[(k0+7)*DIM+c];
        sa[0] += lnw[k0+0]*w0; ta[0] += lnb[k0+0]*w0;
        sa[1] += lnw[k0+1]*w1; ta[1] += lnb[k0+1]*w1;
        sa[2] += lnw[k0+2]*w2; ta[2] += lnb[k0+2]*w2;
        sa[3] += lnw[k0+3]*w3; ta[3] += lnb[k0+3]*w3;
        sa[4] += lnw[k0+4]*w4; ta[4] += lnb[k0+4]*w4;
        sa[5] += lnw[k0+5]*w5; ta[5] += lnb[k0+5]*w5;
        sa[6] += lnw[k0+6]*w6; ta[6] += lnb[k0+6]*w6;
        sa[7] += lnw[k0+7]*w7; ta[7] += lnb[k0+7]*w7;
    }
    const float s = ((sa[0]+sa[1])+(sa[2]+sa[3]))+((sa[4]+sa[5])+(sa[6]+sa[7]));
    const float t = ((ta[0]+ta[1])+(ta[2]+ta[3]))+((ta[4]+ta[5])+(ta[6]+ta[7]));
    const float qs = (mat == 0) ? (QSCALE * gate[c >> 5]) : 1.0f;
    scol[mat * DIM + c] = s * qs;
    tcol[mat * DIM + c] = (t + bias[c]) * qs;
}

// sum/sumsq of one float4 pair
#define ACC8(p, q) do { \
    s  += ((p.x + p.y) + (p.z + p.w)) + ((q.x + q.y) + (q.z + q.w)); \
    s2 += ((p.x*p.x + p.y*p.y) + (p.z*p.z + p.w*p.w)) \
        + ((q.x*q.x + q.y*q.y) + (q.z*q.z + q.w*q.w)); } while (0)
#define CVT8(p, q) ({ short8 o_; \
    o_[0]=(short)f2bf(p.x); o_[1]=(short)f2bf(p.y); o_[2]=(short)f2bf(p.z); o_[3]=(short)f2bf(p.w); \
    o_[4]=(short)f2bf(q.x); o_[5]=(short)f2bf(q.y); o_[6]=(short)f2bf(q.z); o_[7]=(short)f2bf(q.w); o_; })

// ---------------------------------------------------------------------------
// Fused MFMA projection v8 (r18-exact, best measured: total 70.5us):
// out = rsig*(x@W') - rsig*mu*s + t. 384-thread blocks (6 waves x 2 units),
// grid 768 = 3 blocks/CU.
// ---------------------------------------------------------------------------
__global__ __launch_bounds__(384) void proj_kernel(
    const float* __restrict__ qx, const float* __restrict__ kx,
    const float* __restrict__ vx,
    const unsigned short* __restrict__ wt,
    const float* __restrict__ scol, const float* __restrict__ tcol,
    unsigned short* __restrict__ qh, unsigned short* __restrict__ kh,
    unsigned short* __restrict__ vh)
{
    __shared__ unsigned short Wl[DIM * DIM];      // 32 KB swizzled [col][k]

    const int bid  = blockIdx.x;              // 768 = mode*256 + rr
    const int mode = bid >> 8;
    const int rr   = bid & 255;               // b*128 + l*2 + ng
    const int b = rr >> 7, l = (rr >> 1) & 63, ng = rr & 1;

    const float* xin = (mode == 0) ? qx : (mode == 1) ? kx : vx;
    const unsigned short* wtm = wt + (mode << 14);
    const float* sc = scol + mode * DIM;
    const float* tc = tcol + mode * DIM;
    unsigned short* outp = (mode == 0) ? qh : (mode == 1) ? kh : vh;

    const int wv_ = threadIdx.x / 64;         // 0..5
    const int lane = threadIdx.x & 63;
    const int g = lane >> 4, qc = lane & 15;
    const int n  = ng * 3 + (wv_ >> 1);       // agent
    const int t0 = (wv_ & 1) * 32;            // 32-token slice of agent n

    // ---- issue ALL global loads up front: 6 W chunks + 16 x float4 ----
    short8 wbuf0 = {0,0,0,0,0,0,0,0}, wbuf1 = wbuf0, wbuf2 = wbuf0,
           wbuf3 = wbuf0, wbuf4 = wbuf0, wbuf5 = wbuf0;
    {
        const int e0 = threadIdx.x;
        wbuf0 = *(const short8*)&wtm[(e0 +    0) * 8];
        wbuf1 = *(const short8*)&wtm[(e0 +  384) * 8];
        wbuf2 = *(const short8*)&wtm[(e0 +  768) * 8];
        wbuf3 = *(const short8*)&wtm[(e0 + 1152) * 8];
        wbuf4 = *(const short8*)&wtm[(e0 + 1536) * 8];
        if (e0 + 1920 < 2048) wbuf5 = *(const short8*)&wtm[(e0 + 1920) * 8];
    }

    const float* xp0 = xin + ((size_t)((b * NA + n) * NWIN + l) * 64 + t0 + qc) * DIM + 8 * g;
    const float* xp1 = xp0 + 16 * DIM;
    const float4 u0 = *(const float4*)(xp0 + 0);
    const float4 u1 = *(const float4*)(xp0 + 4);
    const float4 u2 = *(const float4*)(xp0 + 32);
    const float4 u3 = *(const float4*)(xp0 + 36);
    const float4 u4 = *(const float4*)(xp0 + 64);
    const float4 u5 = *(const float4*)(xp0 + 68);
    const float4 u6 = *(const float4*)(xp0 + 96);
    const float4 u7 = *(const float4*)(xp0 + 100);
    const float4 y0 = *(const float4*)(xp1 + 0);
    const float4 y1 = *(const float4*)(xp1 + 4);
    const float4 y2 = *(const float4*)(xp1 + 32);
    const float4 y3 = *(const float4*)(xp1 + 36);
    const float4 y4 = *(const float4*)(xp1 + 64);
    const float4 y5 = *(const float4*)(xp1 + 68);
    const float4 y6 = *(const float4*)(xp1 + 96);
    const float4 y7 = *(const float4*)(xp1 + 100);

    // ---- W -> LDS (swizzled) ----
    {
        const int e0 = threadIdx.x;
#define WSTORE(eo, bufv) do { const int e_ = e0 + eo; \
        const int col_ = e_ >> 4, k8_ = (e_ & 15) * 8; \
        *(short8*)&Wl[col_ * DIM + (k8_ ^ ((col_ & 7) << 3))] = bufv; } while (0)
        WSTORE(0, wbuf0); WSTORE(384, wbuf1); WSTORE(768, wbuf2);
        WSTORE(1152, wbuf3); WSTORE(1536, wbuf4);
        if (e0 + 1920 < 2048) WSTORE(1920, wbuf5);
#undef WSTORE
    }

    // ---- stats (overlap the LDS writes) ----
    float mu0, rs0, mu1, rs1;
    {
        float s = 0.f, s2 = 0.f;
        ACC8(u0, u1); ACC8(u2, u3); ACC8(u4, u5); ACC8(u6, u7);
        s  += __shfl_xor(s, 16);  s  += __shfl_xor(s, 32);
        s2 += __shfl_xor(s2, 16); s2 += __shfl_xor(s2, 32);
        mu0 = s * (1.0f / 128.0f);
        rs0 = rsqrtf(s2 * (1.0f / 128.0f) - mu0 * mu0 + 1e-5f);
    }
    {
        float s = 0.f, s2 = 0.f;
        ACC8(y0, y1); ACC8(y2, y3); ACC8(y4, y5); ACC8(y6, y7);
        s  += __shfl_xor(s, 16);  s  += __shfl_xor(s, 32);
        s2 += __shfl_xor(s2, 16); s2 += __shfl_xor(s2, 32);
        mu1 = s * (1.0f / 128.0f);
        rs1 = rsqrtf(s2 * (1.0f / 128.0f) - mu1 * mu1 + 1e-5f);
    }

    short8 af0[4], af1[4];
    af0[0] = CVT8(u0, u1); af0[1] = CVT8(u2, u3);
    af0[2] = CVT8(u4, u5); af0[3] = CVT8(u6, u7);
    af1[0] = CVT8(y0, y1); af1[1] = CVT8(y2, y3);
    af1[2] = CVT8(y4, y5); af1[3] = CVT8(y6, y7);
    __syncthreads();    // W staged

    // v-mode needs stats of tokens 4g+r (rows of unswapped D) per lane
    float m0[4], r0[4], m1[4], r1[4];
    if (mode == 2) {
#pragma unroll
        for (int r = 0; r < 4; ++r) {
            m0[r] = __shfl(mu0, 4 * g + r); r0[r] = __shfl(rs0, 4 * g + r);
            m1[r] = __shfl(mu1, 4 * g + r); r1[r] = __shfl(rs1, 4 * g + r);
        }
    }

    const f32x4 z = {0.f, 0.f, 0.f, 0.f};
    const int swz = (qc & 7) << 3;            // col&7 == qc&7 (ct*16 ≡ 0 mod 8)

#pragma unroll
    for (int ct = 0; ct < 8; ++ct) {
        const int col = ct * 16 + qc;
        short8 wf[4];
#pragma unroll
        for (int c = 0; c < 4; ++c)
            wf[c] = *(const short8*)&Wl[col * DIM + ((c * 32 + 8 * g) ^ swz)];

        f32x4 a0 = z, a1 = z;
        if (mode == 2) {
            // unswapped: D rows = tokens (4g+r), col = W-col qc -> [d][t]
#pragma unroll
            for (int c = 0; c < 4; ++c) {
                a0 = __builtin_amdgcn_mfma_f32_16x16x32_bf16(af0[c], wf[c], a0, 0, 0, 0);
                a1 = __builtin_amdgcn_mfma_f32_16x16x32_bf16(af1[c], wf[c], a1, 0, 0, 0);
            }
            const float s_c = sc[col], t_c = tc[col];
            const int head = ct >> 1;
            const int d = (ct & 1) * 16 + qc;
            const size_t rowb = ((size_t)(b * NHEADS + head) * NWIN + l) * DHEAD + d;
            unsigned short* dst = outp + rowb * NTOK + n * 64 + t0 + 4 * g;
            ushort4 o;
            o.x = f2bf(r0[0] * (a0[0] - m0[0] * s_c) + t_c);
            o.y = f2bf(r0[1] * (a0[1] - m0[1] * s_c) + t_c);
            o.z = f2bf(r0[2] * (a0[2] - m0[2] * s_c) + t_c);
            o.w = f2bf(r0[3] * (a0[3] - m0[3] * s_c) + t_c);
            *(ushort4*)&dst[0] = o;
            o.x = f2bf(r1[0] * (a1[0] - m1[0] * s_c) + t_c);
            o.y = f2bf(r1[1] * (a1[1] - m1[1] * s_c) + t_c);
            o.z = f2bf(r1[2] * (a1[2] - m1[2] * s_c) + t_c);
            o.w = f2bf(r1[3] * (a1[3] - m1[3] * s_c) + t_c);
            *(ushort4*)&dst[16] = o;
        } else {
            // swapped: D^T -> lane = token qc, cols ct*16+4g..+3 (contig)
#pragma unroll
            for (int c = 0; c < 4; ++c) {
                a0 = __builtin_amdgcn_mfma_f32_16x16x32_bf16(wf[c], af0[c], a0, 0, 0, 0);
                a1 = __builtin_amdgcn_mfma_f32_16x16x32_bf16(wf[c], af1[c], a1, 0, 0, 0);
            }
            const int head = ct >> 1;
            const int d0 = (ct & 1) * 16 + 4 * g;
            const float4 s4 = *(const float4*)&sc[ct * 16 + 4 * g];
            const float4 t4 = *(const float4*)&tc[ct * 16 + 4 * g];
            const size_t hb = (size_t)(b * NHEADS + head) * NWIN + l;
            unsigned short* dst = outp + (hb * NTOK + n * 64 + t0 + qc) * DHEAD + d0;
            ushort4 o;
            o.x = f2bf(rs0 * (a0[0] - mu0 * s4.x) + t4.x);
            o.y = f2bf(rs0 * (a0[1] - mu0 * s4.y) + t4.y);
            o.z = f2bf(rs0 * (a0[2] - mu0 * s4.z) + t4.z);
            o.w = f2bf(rs0 * (a0[3] - mu0 * s4.w) + t4.w);
            *(ushort4*)&dst[0] = o;
            o.x = f2bf(rs1 * (a1[0] - mu1 * s4.x) + t4.x);
            o.y = f2bf(rs1 * (a1[1] - mu1 * s4.y) + t4.y);
            o.z = f2bf(rs1 * (a1[2] - mu1 * s4.z) + t4.z);
            o.w = f2bf(rs1 * (a1[3] - mu1 * s4.w) + t4.w);
            *(ushort4*)&dst[16 * DHEAD] = o;
        }
    }
}

// ---------------------------------------------------------------------------
// MFMA flash attention v4 (r18-exact): one block per (b,h,l,q-half), 4 waves
// x 3 q-tiles, P via barrier-free padded LDS, XCD pair-swizzle, __expf.
// ---------------------------------------------------------------------------
__global__ __launch_bounds__(256) void attn_kernel(
    const unsigned short* __restrict__ qh, const unsigned short* __restrict__ kh,
    const unsigned short* __restrict__ vt, unsigned short* __restrict__ aout)
{
    __shared__ unsigned short P[4][3][16][40];   // 15 KB

    const int tid  = threadIdx.x;
    const int w    = tid >> 6;
    const int lane = tid & 63;
    const int g    = lane >> 4;
    const int qc   = lane & 15;

    const int raw = blockIdx.x;                  // 1024
    const int p    = (raw >> 4) * 8 + (raw & 7); // pair id 0..511
    const int half = (raw >> 3) & 1;
    const int b = p >> 8, h = (p >> 6) & 3, l = p & 63;
    const size_t base = (size_t)((b * NHEADS + h) * NWIN + l) * (NTOK * DHEAD);
    const unsigned short* Qp = qh + base;
    const unsigned short* Kp = kh + base;
    const unsigned short* Vp = vt + base;        // [32][384]

    short8 qf[3];
#pragma unroll
    for (int j = 0; j < 3; ++j)
        qf[j] = *(const short8*)(Qp + (size_t)(((half * 4 + w) * 3 + j) * 16 + qc) * DHEAD + 8 * g);

    f32x4 o0[3], o1[3];
    float psum[3];
    const f32x4 z = {0.f, 0.f, 0.f, 0.f};
#pragma unroll
    for (int j = 0; j < 3; ++j) { o0[j] = z; o1[j] = z; psum[j] = 0.f; }

    for (int kc = 0; kc < 12; ++kc) {
        const int k0 = kc * 32;
        const short8 ka0 = *(const short8*)(Kp + (size_t)(k0 + qc) * DHEAD + 8 * g);
        const short8 ka1 = *(const short8*)(Kp + (size_t)(k0 + 16 + qc) * DHEAD + 8 * g);
        const short8 vb0 = *(const short8*)(Vp + (size_t)qc * NTOK + k0 + 8 * g);
        const short8 vb1 = *(const short8*)(Vp + (size_t)(16 + qc) * NTOK + k0 + 8 * g);

#pragma unroll
        for (int j = 0; j < 3; ++j) {
            f32x4 s0 = __builtin_amdgcn_mfma_f32_16x16x32_bf16(ka0, qf[j], z, 0, 0, 0);
            f32x4 s1 = __builtin_amdgcn_mfma_f32_16x16x32_bf16(ka1, qf[j], z, 0, 0, 0);
            const float e0 = __expf(s0[0]), e1 = __expf(s0[1]), e2 = __expf(s0[2]), e3 = __expf(s0[3]);
            const float e4 = __expf(s1[0]), e5 = __expf(s1[1]), e6 = __expf(s1[2]), e7 = __expf(s1[3]);
            psum[j] += ((e0 + e1) + (e2 + e3)) + ((e4 + e5) + (e6 + e7));
            ushort4 pw0, pw1;
            pw0.x = f2bf(e0); pw0.y = f2bf(e1); pw0.z = f2bf(e2); pw0.w = f2bf(e3);
            pw1.x = f2bf(e4); pw1.y = f2bf(e5); pw1.z = f2bf(e6); pw1.w = f2bf(e7);
            *(ushort4*)&P[w][j][qc][4 * g]      = pw0;
            *(ushort4*)&P[w][j][qc][16 + 4 * g] = pw1;
        }
#pragma unroll
        for (int j = 0; j < 3; ++j) {
            const short8 pa = *(const short8*)&P[w][j][qc][8 * g];
            o0[j] = __builtin_amdgcn_mfma_f32_16x16x32_bf16(pa, vb0, o0[j], 0, 0, 0);
            o1[j] = __builtin_amdgcn_mfma_f32_16x16x32_bf16(pa, vb1, o1[j], 0, 0, 0);
        }
    }

#pragma unroll
    for (int j = 0; j < 3; ++j) {
        float ps = psum[j];
        ps += __shfl_xor(ps, 16);
        ps += __shfl_xor(ps, 32);
        const float inv = 1.0f / ps;
        const int q0 = ((half * 4 + w) * 3 + j) * 16;
        const size_t ob = ((size_t)(b * NWIN + l) * NTOK + q0) * (NHEADS * DHEAD) + h * DHEAD + qc;
#pragma unroll
        for (int r = 0; r < 4; ++r) {
            const float iv = __shfl(inv, 4 * g + r);
            aout[ob + (size_t)(4 * g + r) * (NHEADS * DHEAD)]      = f2bf(o0[j][r] * iv);
            aout[ob + (size_t)(4 * g + r) * (NHEADS * DHEAD) + 16] = f2bf(o1[j][r] * iv);
        }
    }
}

// ---------------------------------------------------------------------------
// Output projection: mean over n commutes with (@ wp + bp). One block per
// (b, window, col-half) -> 256 blocks. a is bf16.
// ---------------------------------------------------------------------------
__global__ __launch_bounds__(256) void outproj_kernel(
    const unsigned short* __restrict__ a, const float* __restrict__ wp,
    const float* __restrict__ bp, const float* __restrict__ skip,
    float* __restrict__ outp)
{
    __shared__ float at[DIM * 68];       // abar transposed [dim][w], 34 KB
    __shared__ float wl[DIM * 64];       // [k][64 cols] 32 KB

    const int tid = threadIdx.x;
    const int bid = blockIdx.x;
    const int b = bid >> 7, l = (bid >> 1) & 63, cg = bid & 1;
    const int c0 = cg * 64;

#pragma unroll
    for (int rep = 0; rep < 8; ++rep) {
        const int idx = rep * 256 + tid;
        const int row = idx >> 4, cc4 = idx & 15;
        *(float4*)&wl[row * 64 + cc4 * 4] = *(const float4*)&wp[row * 128 + c0 + cc4 * 4];
    }

    const size_t abase = (size_t)(b * NWIN + l) * NTOK * DIM;
#pragma unroll
    for (int r = 0; r < 32; ++r) {
        const int f = tid + 256 * r;     // f = w*128 + d
        const int w_ = f >> 7, d = f & 127;
        float s = 0.f;
#pragma unroll
        for (int n = 0; n < NA; ++n)
            s += bf2f(a[abase + (size_t)(n * 64 + w_) * DIM + d]);
        at[d * 68 + w_] = s * (1.0f / 6.0f);
    }
    __syncthreads();

    const int cx = tid & 15, ty = tid >> 4;   // 4 cols x 4 tokens per thread
    float acc[4][4];
#pragma unroll
    for (int i = 0; i < 4; ++i)
#pragma unroll
        for (int j = 0; j < 4; ++j) acc[i][j] = 0.f;

#pragma unroll 4
    for (int i = 0; i < DIM; ++i) {
        const float4 wa = *(const float4*)&wl[i * 64 + 4 * cx];
        const float4 aa = *(const float4*)&at[i * 68 + 4 * ty];
        acc[0][0] += aa.x * wa.x; acc[0][1] += aa.x * wa.y; acc[0][2] += aa.x * wa.z; acc[0][3] += aa.x * wa.w;
        acc[1][0] += aa.y * wa.x; acc[1][1] += aa.y * wa.y; acc[1][2] += aa.y * wa.z; acc[1][3] += aa.y * wa.w;
        acc[2][0] += aa.z * wa.x; acc[2][1] += aa.z * wa.y; acc[2][2] += aa.z * wa.z; acc[2][3] += aa.z * wa.w;
        acc[3][0] += aa.w * wa.x; acc[3][1] += aa.w * wa.y; acc[3][2] += aa.w * wa.z; acc[3][3] += aa.w * wa.w;
    }

    const float4 bb = *(const float4*)&bp[c0 + 4 * cx];
#pragma unroll
    for (int u = 0; u < 4; ++u) {
        const int w_ = 4 * ty + u;
        const size_t oidx = ((size_t)(b * NWIN + l) * 64 + w_) * DIM + c0 + 4 * cx;
        const float4 sk = *(const float4*)&skip[oidx];
        float4 o;
        o.x = acc[u][0] + bb.x + sk.x;
        o.y = acc[u][1] + bb.y + sk.y;
        o.z = acc[u][2] + bb.z + sk.z;
        o.w = acc[u][3] + bb.w + sk.w;
        *(float4*)&outp[oidx] = o;
    }
}

extern "C" void kernel_launch(void* const* d_in, const int* in_sizes, int n_in,
                              void* d_out, int out_size, void* d_ws, size_t ws_size,
                              hipStream_t stream) {
    const float* q      = (const float*)d_in[0];
    const float* k      = (const float*)d_in[1];
    const float* v      = (const float*)d_in[2];
    const float* skip   = (const float*)d_in[3];
    const float* gate   = (const float*)d_in[4];
    const float* ln_q_w = (const float*)d_in[5];
    const float* ln_q_b = (const float*)d_in[6];
    const float* ln_k_w = (const float*)d_in[7];
    const float* ln_k_b = (const float*)d_in[8];
    const float* ln_v_w = (const float*)d_in[9];
    const float* ln_v_b = (const float*)d_in[10];
    const float* wq     = (const float*)d_in[11];
    const float* bq     = (const float*)d_in[12];
    const float* wk     = (const float*)d_in[13];
    const float* bk     = (const float*)d_in[14];
    const float* wv     = (const float*)d_in[15];
    const float* bv     = (const float*)d_in[16];
    const float* wp     = (const float*)d_in[17];
    const float* bp     = (const float*)d_in[18];
    float* outp = (float*)d_out;

    const size_t per = (size_t)NB * NHEADS * NWIN * NTOK * DHEAD;  // 6,291,456
    unsigned short* qh = (unsigned short*)d_ws;
    unsigned short* kh = qh + per;
    unsigned short* vh = kh + per;
    unsigned short* wt = vh + per;                 // 3*16384 bf16
    unsigned short* a  = wt + 3 * 16384;           // [b][l][t][128] bf16
    float* scol = (float*)(a + per);               // 3*128 f32
    float* tcol = scol + 3 * DIM;

    wprep_kernel<<<195, 256, 0, stream>>>(wq, wk, wv, ln_q_w, ln_k_w, ln_v_w,
                                          ln_q_b, ln_k_b, ln_v_b, bq, bk, bv,
                                          gate, wt, scol, tcol);
    proj_kernel<<<768, 384, 0, stream>>>(q, k, v, wt, scol, tcol, qh, kh, vh);
    attn_kernel<<<NB * NHEADS * NWIN * 2, 256, 0, stream>>>(qh, kh, vh, a);
    outproj_kernel<<<NB * NWIN * 2, 256, 0, stream>>>(a, wp, bp, skip, outp);
}